// Round 5
// baseline (49.704 us; speedup 1.0000x reference)
//
#include <hip/hip_runtime.h>
#include <math.h>

// SPSA on f(x) = x0^2 + Q*x1^2, Q=8. Step is affine: x' = S(d,k) x,
//   S = I + [nw; nw*s] * [1, Q*s],  nw = -2*ak, s = d0*d1 in {-1,+1}.
//   ck cancels exactly. x_final = (prod_k S_k) x_init.
// 32 segments x ~32 steps, 8192 waves, one 32-load burst per thread,
// ORDER-PRESERVING in-place pairwise LDS tree combine (R4 lesson: the
// M[i] <- M[i+h]*M[i] fold is wrong for non-commutative 2x2 products).

#define BLK  256
#define TPJ  8            // trajectories per block
#define NSEG 32           // segments (= threads per trajectory)

__global__ __launch_bounds__(BLK, 4) void spsa_kernel(
    const float2* __restrict__ X0,
    const int2*   __restrict__ bits,   // (n, bs) int2 of {0,1} bits
    const float*  __restrict__ a_arr,
    float2*       __restrict__ out,
    int n, int bs, int A)
{
    __shared__ float  s_nw[1024];        // n <= 1024 (n = 1000 here)
    __shared__ float4 s_m[NSEG][TPJ];

    const int tid  = threadIdx.x;
    const int traj = tid & (TPJ - 1);
    const int seg  = tid >> 3;           // 0..31
    int b          = blockIdx.x * TPJ + traj;
    const bool act = (b < bs);
    if (!act) b = bs - 1;                // clamp for safe (discarded) loads

    const int seglen = (n + NSEG - 1) / NSEG;    // 32 for n=1000 (<=32 req'd)
    const int k0 = seg * seglen;

    const int2* p = bits + (size_t)k0 * bs + b;

    // Issue the whole segment's loads up front (64 VGPRs in flight).
    int2 v[32];
    #pragma unroll
    for (int j = 0; j < 32; ++j)
        if (j < seglen && k0 + j < n) v[j] = p[(size_t)j * bs];

    // Coefficient table while loads are in flight: nw[k] = -2*a[k]/(k+2+A)^0.602
    for (int k = tid; k < n; k += BLK) {
        float base = (float)(k + 2 + A);
        s_nw[k] = -2.0f * a_arr[k] / powf(base, 0.602f);
    }

    // Segment product M = S_{k0+cnt-1} * ... * S_{k0}, row-major 2x2.
    float m00 = 1.f, m01 = 0.f, m10 = 0.f, m11 = 1.f;

    auto step = [&](int2 d, float nw) {
        unsigned sb = ((unsigned)(d.x ^ d.y)) << 31;        // sign of s
        float qs  = __uint_as_float(0x41000000u ^ sb);      // +-8.0
        float nws = __uint_as_float(__float_as_uint(nw) ^ sb);
        float u0 = fmaf(qs, m10, m00);                      // [1,qs] . M
        float u1 = fmaf(qs, m11, m01);
        m00 = fmaf(nw,  u0, m00);
        m01 = fmaf(nw,  u1, m01);
        m10 = fmaf(nws, u0, m10);
        m11 = fmaf(nws, u1, m11);
    };

    __syncthreads();                     // s_nw ready
    #pragma unroll
    for (int j = 0; j < 32; ++j)
        if (j < seglen && k0 + j < n) step(v[j], s_nw[k0 + j]);

    s_m[seg][traj] = make_float4(m00, m01, m10, m11);

    // Order-preserving in-place pairwise tree:
    //   level lvl (stride str): s_m[p] <- s_m[p+str] * s_m[p], p = 2*seg*str.
    // Left operand = earlier segments (right side of product), so the later
    // block multiplies from the LEFT — sequential ordering preserved.
    // Writes touch even multiples of str only; cross-thread reads touch odd
    // multiples only -> no intra-level race; barrier per level.
    #pragma unroll
    for (int lvl = 0; lvl < 5; ++lvl) {
        const int str = 1 << lvl;
        const int h   = NSEG >> (lvl + 1);
        __syncthreads();
        if (seg < h) {
            const int pos = (seg * 2) * str;
            float4 L = s_m[pos][traj];
            float4 R = s_m[pos + str][traj];
            float4 P;
            P.x = fmaf(R.x, L.x, R.y * L.z);
            P.y = fmaf(R.x, L.y, R.y * L.w);
            P.z = fmaf(R.z, L.x, R.w * L.z);
            P.w = fmaf(R.z, L.y, R.w * L.w);
            s_m[pos][traj] = P;
        }
    }

    if (seg == 0 && act) {               // same threads wrote s_m[0][traj]
        float4 M = s_m[0][traj];
        float2 xin = X0[b];
        float v0 = xin.x * 20.0f - 10.0f;
        float v1 = xin.y * 20.0f - 10.0f;
        float r0 = fmaf(M.x, v0, M.y * v1);
        float r1 = fmaf(M.z, v0, M.w * v1);
        out[b] = make_float2(r0, r1);
    }
}

extern "C" void kernel_launch(void* const* d_in, const int* in_sizes, int n_in,
                              void* d_out, int out_size, void* d_ws, size_t ws_size,
                              hipStream_t stream) {
    const float2* X0   = (const float2*)d_in[0];
    const float*  a    = (const float*) d_in[1];
    // d_in[2] = c (cancels exactly, unused)
    const int2*   bits = (const int2*)  d_in[3];
    float2*       out  = (float2*)d_out;

    const int bs = in_sizes[0] / 2;
    const int n  = in_sizes[1];
    const int A  = (int)floor(0.1 * (double)n);

    const int grid = (bs + TPJ - 1) / TPJ;
    spsa_kernel<<<grid, BLK, 0, stream>>>(X0, bits, a, out, n, bs, A);
}

// Round 6
// 47.864 us; speedup vs baseline: 1.0384x; 1.0384x over previous
//
#include <hip/hip_runtime.h>
#include <math.h>

// SPSA on f(x) = x0^2 + Q*x1^2, Q=8. Step is affine: x' = S(d,k) x,
//   S = I + [nw; nw*s] * [1, Q*s],  nw = -2*ak, s = d0*d1 in {-1,+1}.
//   ck cancels exactly. x_final = (prod_k S_k) x_init.
// 32 segments x 32 steps (compile-time), 8192 waves, one UNCONDITIONAL
// 32-load burst per thread (R5 lesson: runtime-predicated loads killed the
// burst -> VGPR=52, 1.7 TB/s). Out-of-range k: load index clamped to n-1,
// nw table zero-padded (nw=0 -> S=I exactly). Order-preserving pairwise
// LDS tree with +seg column swizzle (R5: 1.58M bank conflicts unswizzled).

#define BLK    256
#define TPJ    8            // trajectories per block
#define NSEG   32           // segments (threads per trajectory)
#define SEGLEN 32           // steps per segment (compile-time!)
#define NTAB   (NSEG * SEGLEN)   // 1024; main kernel requires n <= NTAB

__global__ __launch_bounds__(BLK, 4) void spsa_kernel(
    const float2* __restrict__ X0,
    const int2*   __restrict__ bits,   // (n, bs) int2 of {0,1} bits
    const float*  __restrict__ a_arr,
    float2*       __restrict__ out,
    int n, int bs, int A)
{
    __shared__ float  s_nw[NTAB];        // zero-padded past n
    __shared__ float4 s_m[NSEG][TPJ];

    const int tid  = threadIdx.x;
    const int traj = tid & (TPJ - 1);
    const int seg  = tid >> 3;           // 0..31
    int b          = blockIdx.x * TPJ + traj;
    const bool act = (b < bs);
    if (!act) b = bs - 1;                // clamp for safe (discarded) loads

    const int k0   = seg * SEGLEN;
    const int kmax = n - 1;
    const int2* pbase = bits + b;

    // Unconditional 32-load burst (index clamped; padded steps are identity).
    int2 v[SEGLEN];
    #pragma unroll
    for (int j = 0; j < SEGLEN; ++j) {
        int k = k0 + j;
        k = (k > kmax) ? kmax : k;
        v[j] = pbase[(size_t)k * bs];
    }

    // Coefficient table while loads are in flight:
    //   nw[k] = -2*a[k]/(k+2+A)^0.602 for k<n, else 0 (identity step).
    for (int k = tid; k < NTAB; k += BLK) {
        float base = (float)(k + 2 + A);
        s_nw[k] = (k < n) ? (-2.0f * a_arr[k] / powf(base, 0.602f)) : 0.0f;
    }

    // Segment product M = S_{k0+31} * ... * S_{k0}, row-major 2x2.
    float m00 = 1.f, m01 = 0.f, m10 = 0.f, m11 = 1.f;

    auto step = [&](int2 d, float nw) {
        unsigned sb = ((unsigned)(d.x ^ d.y)) << 31;        // sign of s
        float qs  = __uint_as_float(0x41000000u ^ sb);      // +-8.0
        float nws = __uint_as_float(__float_as_uint(nw) ^ sb);
        float u0 = fmaf(qs, m10, m00);                      // [1,qs] . M
        float u1 = fmaf(qs, m11, m01);
        m00 = fmaf(nw,  u0, m00);
        m01 = fmaf(nw,  u1, m01);
        m10 = fmaf(nws, u0, m10);
        m11 = fmaf(nws, u1, m11);
    };

    __syncthreads();                     // s_nw ready
    #pragma unroll
    for (int j = 0; j < SEGLEN; ++j) step(v[j], s_nw[k0 + j]);

    // Swizzled column: lanes of one 8-lane group hit 32 distinct banks.
    s_m[seg][(traj + seg) & (TPJ - 1)] = make_float4(m00, m01, m10, m11);

    // Order-preserving in-place pairwise tree:
    //   level lvl (stride str): s_m[p] <- s_m[p+str] * s_m[p], p = 2*seg*str.
    // Writes touch even multiples of 2*str; cross-thread reads touch odd
    // multiples of str -> no intra-level race; barrier per level.
    #pragma unroll
    for (int lvl = 0; lvl < 5; ++lvl) {
        const int str = 1 << lvl;
        const int h   = NSEG >> (lvl + 1);
        __syncthreads();
        if (seg < h) {
            const int pos = (seg * 2) * str;
            float4 L = s_m[pos]      [(traj + pos)       & (TPJ - 1)];
            float4 R = s_m[pos + str][(traj + pos + str) & (TPJ - 1)];
            float4 P;
            P.x = fmaf(R.x, L.x, R.y * L.z);
            P.y = fmaf(R.x, L.y, R.y * L.w);
            P.z = fmaf(R.z, L.x, R.w * L.z);
            P.w = fmaf(R.z, L.y, R.w * L.w);
            s_m[pos][(traj + pos) & (TPJ - 1)] = P;
        }
    }

    if (seg == 0 && act) {
        float4 M = s_m[0][traj];
        float2 xin = X0[b];
        float v0 = xin.x * 20.0f - 10.0f;
        float v1 = xin.y * 20.0f - 10.0f;
        float r0 = fmaf(M.x, v0, M.y * v1);
        float r1 = fmaf(M.z, v0, M.w * v1);
        out[b] = make_float2(r0, r1);
    }
}

// Correctness fallback for n > NTAB (never hit in this bench: n = 1000).
__global__ void spsa_fallback(
    const float2* __restrict__ X0, const int2* __restrict__ bits,
    const float* __restrict__ a_arr, float2* __restrict__ out,
    int n, int bs, int A)
{
    int b = blockIdx.x * 256 + threadIdx.x;
    if (b >= bs) return;
    float2 xin = X0[b];
    float x0 = xin.x * 20.0f - 10.0f;
    float x1 = xin.y * 20.0f - 10.0f;
    for (int k = 0; k < n; ++k) {
        float nw = -2.0f * a_arr[k] / powf((float)(k + 2 + A), 0.602f);
        int2 d = bits[(size_t)k * bs + b];
        unsigned sb = ((unsigned)(d.x ^ d.y)) << 31;
        float qs  = __uint_as_float(0x41000000u ^ sb);
        float nws = __uint_as_float(__float_as_uint(nw) ^ sb);
        float u = fmaf(qs, x1, x0);
        x0 = fmaf(nw,  u, x0);
        x1 = fmaf(nws, u, x1);
    }
    out[b] = make_float2(x0, x1);
}

extern "C" void kernel_launch(void* const* d_in, const int* in_sizes, int n_in,
                              void* d_out, int out_size, void* d_ws, size_t ws_size,
                              hipStream_t stream) {
    const float2* X0   = (const float2*)d_in[0];
    const float*  a    = (const float*) d_in[1];
    // d_in[2] = c (cancels exactly, unused)
    const int2*   bits = (const int2*)  d_in[3];
    float2*       out  = (float2*)d_out;

    const int bs = in_sizes[0] / 2;
    const int n  = in_sizes[1];
    const int A  = (int)floor(0.1 * (double)n);

    if (n <= NTAB) {
        const int grid = (bs + TPJ - 1) / TPJ;
        spsa_kernel<<<grid, BLK, 0, stream>>>(X0, bits, a, out, n, bs, A);
    } else {
        const int grid = (bs + 255) / 256;
        spsa_fallback<<<grid, 256, 0, stream>>>(X0, bits, a, out, n, bs, A);
    }
}

// Round 7
// 29.927 us; speedup vs baseline: 1.6608x; 1.5993x over previous
//
#include <hip/hip_runtime.h>
#include <math.h>

// SPSA on f(x) = x0^2 + Q*x1^2, Q=8. Step is affine: x' = S(d,k) x,
//   S = I + [nw; nw*s] * [1, Q*s],  nw = -2*ak, s = d0*d1 in {-1,+1}.
//   ck cancels exactly. x_final = (prod_k S_k) x_init.
//
// Two-kernel split (R6 lesson: VGPR cap made the compiler serialize the
// load burst; R5/R6 ~48us == no burst; uncapped R3 = 32us):
//  k1: (bs/64 x 32seg) grid, 64-thr blocks, UNCAPPED, 32 unconditional
//      dwordx2 loads/thread, wave reads 512B contiguous. ws <- 2x2 products.
//  k2: order-preserving LDS tree fold of 32 matrices/traj (verified in R6).

#define SEGLEN 32
#define NSEG   32
#define NTAB   (NSEG * SEGLEN)   // 1024; main path requires n <= NTAB
#define TPJ    8                 // trajectories per block in combine kernel

__global__ __launch_bounds__(64) void seg_kernel(
    const int2*  __restrict__ bits,    // (n, bs) int2 of {0,1} bits
    const float* __restrict__ a_arr,
    float4*      __restrict__ ws,      // (NSEG, bs) segment matrices
    int n, int bs, int A)
{
    __shared__ float s_nw[SEGLEN];

    const int lane = threadIdx.x;
    int b          = blockIdx.x * 64 + lane;
    if (b >= bs) b = bs - 1;               // safe clamp (bs % 64 == 0 normally)
    const int seg  = blockIdx.y;
    const int k0   = seg * SEGLEN;
    const int kmax = n - 1;

    // Unconditional 32-load burst; index clamped, padded steps get nw=0.
    const int2* p = bits + b;
    int2 v[SEGLEN];
    #pragma unroll
    for (int j = 0; j < SEGLEN; ++j) {
        int k = k0 + j;
        k = (k > kmax) ? kmax : k;
        v[j] = p[(size_t)k * bs];
    }

    // Per-block coefficient table while loads are in flight:
    //   nw[k] = -2*a[k]/(k+2+A)^0.602 for k<n, else 0 (identity step).
    if (lane < SEGLEN) {
        const int k = k0 + lane;
        float nw = 0.0f;
        if (k < n) nw = -2.0f * a_arr[k] / powf((float)(k + 2 + A), 0.602f);
        s_nw[lane] = nw;
    }
    __syncthreads();

    // Segment product M = S_{k0+31} * ... * S_{k0}, row-major 2x2.
    float m00 = 1.f, m01 = 0.f, m10 = 0.f, m11 = 1.f;
    #pragma unroll
    for (int j = 0; j < SEGLEN; ++j) {
        const int2 d  = v[j];
        const float nw = s_nw[j];
        unsigned sb = ((unsigned)(d.x ^ d.y)) << 31;        // sign of s
        float qs  = __uint_as_float(0x41000000u ^ sb);      // +-8.0
        float nws = __uint_as_float(__float_as_uint(nw) ^ sb);
        float u0 = fmaf(qs, m10, m00);                      // [1,qs] . M
        float u1 = fmaf(qs, m11, m01);
        m00 = fmaf(nw,  u0, m00);
        m01 = fmaf(nw,  u1, m01);
        m10 = fmaf(nws, u0, m10);
        m11 = fmaf(nws, u1, m11);
    }

    ws[(size_t)seg * bs + b] = make_float4(m00, m01, m10, m11);
}

__global__ __launch_bounds__(256) void combine_kernel(
    const float2* __restrict__ X0,
    const float4* __restrict__ ws,     // (NSEG, bs)
    float2*       __restrict__ out,
    int bs)
{
    __shared__ float4 s_m[NSEG][TPJ];

    const int tid  = threadIdx.x;
    const int traj = tid & (TPJ - 1);
    const int seg  = tid >> 3;           // 0..31
    int b          = blockIdx.x * TPJ + traj;
    const bool act = (b < bs);
    if (!act) b = bs - 1;

    // Swizzled column: avoids 8-way bank conflicts on the float4 rows.
    s_m[seg][(traj + seg) & (TPJ - 1)] = ws[(size_t)seg * bs + b];

    // Order-preserving in-place pairwise tree (verified R6):
    //   level lvl (stride str): s_m[p] <- s_m[p+str] * s_m[p], p = 2*seg*str.
    #pragma unroll
    for (int lvl = 0; lvl < 5; ++lvl) {
        const int str = 1 << lvl;
        const int h   = NSEG >> (lvl + 1);
        __syncthreads();
        if (seg < h) {
            const int pos = (seg * 2) * str;
            float4 L = s_m[pos]      [(traj + pos)       & (TPJ - 1)];
            float4 R = s_m[pos + str][(traj + pos + str) & (TPJ - 1)];
            float4 P;
            P.x = fmaf(R.x, L.x, R.y * L.z);
            P.y = fmaf(R.x, L.y, R.y * L.w);
            P.z = fmaf(R.z, L.x, R.w * L.z);
            P.w = fmaf(R.z, L.y, R.w * L.w);
            s_m[pos][(traj + pos) & (TPJ - 1)] = P;
        }
    }

    if (seg == 0 && act) {
        float4 M = s_m[0][traj];
        float2 xin = X0[b];
        float v0 = xin.x * 20.0f - 10.0f;
        float v1 = xin.y * 20.0f - 10.0f;
        float r0 = fmaf(M.x, v0, M.y * v1);
        float r1 = fmaf(M.z, v0, M.w * v1);
        out[b] = make_float2(r0, r1);
    }
}

// Correctness fallback (n > NTAB or tiny ws). Never hit in this bench.
__global__ void spsa_fallback(
    const float2* __restrict__ X0, const int2* __restrict__ bits,
    const float* __restrict__ a_arr, float2* __restrict__ out,
    int n, int bs, int A)
{
    int b = blockIdx.x * 256 + threadIdx.x;
    if (b >= bs) return;
    float2 xin = X0[b];
    float x0 = xin.x * 20.0f - 10.0f;
    float x1 = xin.y * 20.0f - 10.0f;
    for (int k = 0; k < n; ++k) {
        float nw = -2.0f * a_arr[k] / powf((float)(k + 2 + A), 0.602f);
        int2 d = bits[(size_t)k * bs + b];
        unsigned sb = ((unsigned)(d.x ^ d.y)) << 31;
        float qs  = __uint_as_float(0x41000000u ^ sb);
        float nws = __uint_as_float(__float_as_uint(nw) ^ sb);
        float u = fmaf(qs, x1, x0);
        x0 = fmaf(nw,  u, x0);
        x1 = fmaf(nws, u, x1);
    }
    out[b] = make_float2(x0, x1);
}

extern "C" void kernel_launch(void* const* d_in, const int* in_sizes, int n_in,
                              void* d_out, int out_size, void* d_ws, size_t ws_size,
                              hipStream_t stream) {
    const float2* X0   = (const float2*)d_in[0];
    const float*  a    = (const float*) d_in[1];
    // d_in[2] = c (cancels exactly, unused)
    const int2*   bits = (const int2*)  d_in[3];
    float2*       out  = (float2*)d_out;

    const int bs = in_sizes[0] / 2;
    const int n  = in_sizes[1];
    const int A  = (int)floor(0.1 * (double)n);

    const size_t ws_need = (size_t)NSEG * bs * sizeof(float4);
    if (n <= NTAB && ws_size >= ws_need) {
        dim3 g1((bs + 63) / 64, NSEG);
        seg_kernel<<<g1, 64, 0, stream>>>(bits, a, (float4*)d_ws, n, bs, A);
        const int g2 = (bs + TPJ - 1) / TPJ;
        combine_kernel<<<g2, 256, 0, stream>>>(X0, (const float4*)d_ws, out, bs);
    } else {
        const int grid = (bs + 255) / 256;
        spsa_fallback<<<grid, 256, 0, stream>>>(X0, bits, a, out, n, bs, A);
    }
}